// Round 12
// baseline (176.443 us; speedup 1.0000x reference)
//
#include <hip/hip_runtime.h>

typedef float f32x4 __attribute__((ext_vector_type(4)));
typedef short s16x8 __attribute__((ext_vector_type(8)));
typedef unsigned short u16;
typedef unsigned short u16x4 __attribute__((ext_vector_type(4)));
typedef unsigned int u32x2 __attribute__((ext_vector_type(2)));
typedef int i32x4 __attribute__((ext_vector_type(4)));

#define DI __device__ __forceinline__

constexpr int B_ = 2, S_ = 2048, E_ = 1024, H_ = 16, DH = 64, M_ = B_ * S_;
// 1/sqrt(64) * log2(e): scores land in log2 domain -> exp2 for softmax
constexpr float QSCALE = 0.125f * 1.4426950408889634f;

DI u16 f2bf(float f) {
    unsigned u = __float_as_uint(f);
    u += 0x7fffu + ((u >> 16) & 1u);
    return (u16)(u >> 16);
}

DI unsigned cvtpk(float lo, float hi) {
    unsigned r;
    asm("v_cvt_pk_bf16_f32 %0, %1, %2" : "=v"(r) : "v"(lo), "v"(hi));
    return r;
}

DI float max3f(float a, float b, float c) {
    float r;
    asm("v_max3_f32 %0, %1, %2, %3" : "=v"(r) : "v"(a), "v"(b), "v"(c));
    return r;
}

DI void mfma(f32x4& d, s16x8 a, s16x8 b) {
    asm("v_mfma_f32_16x16x32_bf16 %0, %1, %2, %0" : "+v"(d) : "v"(a), "v"(b));
}

typedef __attribute__((address_space(1))) const void gas_cv;
typedef __attribute__((address_space(3))) void las_v;
// async global->LDS, 16B per lane; l must be wave-uniform (HW adds lane*16)
DI void gl16(const void* g, void* l) {
    __builtin_amdgcn_global_load_lds((gas_cv*)g, (las_v*)l, 16, 0, 0);
}

// ---- fused preprocess: cvt_bf16 | wtrans x4 | mexpand2 ------------------
// blocks [0,4096): x->bf16.  [4096,5120): weight transpose (256 blocks per
// weight).  [5120,5376): mask -> wave-coalesced AND-masks.
__global__ __launch_bounds__(256) void prep(const float* __restrict__ x,
                                            u16* __restrict__ xb,
                                            const float* __restrict__ Wq,
                                            const float* __restrict__ Wk,
                                            const float* __restrict__ Wv,
                                            const float* __restrict__ Wo,
                                            u16* __restrict__ Wqkvt,
                                            u16* __restrict__ Wot,
                                            const int* __restrict__ mask,
                                            u32x2* __restrict__ mc) {
    __shared__ float t[64][65];
    const int bid = blockIdx.x;
    if (bid < 4096) {
        int i = bid * 256 + threadIdx.x;
        float4 v = ((const float4*)x)[i];
        u16x4 o;
        o.x = f2bf(v.x); o.y = f2bf(v.y); o.z = f2bf(v.z); o.w = f2bf(v.w);
        ((u16x4*)xb)[i] = o;
    } else if (bid < 5120) {
        const int wb = bid - 4096, w = wb >> 8, rem = wb & 255;
        const float* in = (w == 0) ? Wq : (w == 1) ? Wk : (w == 2) ? Wv : Wo;
        u16* out = (w == 3) ? Wot : Wqkvt + w * 1024 * 1024;
        const int k0 = (rem & 15) * 64, n0 = (rem >> 4) * 64;
        const int tx = threadIdx.x & 63, ty = threadIdx.x >> 6;
#pragma unroll
        for (int i = 0; i < 16; i++) {
            int r = i * 4 + ty;
            t[r][tx] = in[(k0 + r) * E_ + n0 + tx];
        }
        __syncthreads();
#pragma unroll
        for (int i = 0; i < 16; i++) {
            int r = i * 4 + ty;
            out[(n0 + r) * E_ + k0 + tx] = f2bf(t[tx][r]);
        }
    } else {
        // mc[b][qt=q>>4][kt=k>>6][n][lane(g*16+lr)] : u32x2 AND-masks,
        // lane's pair-words for k = kt*64+n*16+g*4+{0..3}, q = qt*16+lr.
        const int bq = bid - 5120;             // b*128 + qt
        const int b = bq >> 7, qt = bq & 127;
        const int tid = threadIdx.x, lane = tid & 63, w = tid >> 6;
        const int lr = lane & 15, g = lane >> 4;
        const int* mrow = mask + ((size_t)(b * S_ + qt * 16 + lr)) * S_;
        u32x2* ob = mc + (size_t)bq * 32 * 4 * 64 + lane;
        for (int kt = w; kt < 32; kt += 4) {
#pragma unroll
            for (int n = 0; n < 4; n++) {
                i32x4 mv = __builtin_nontemporal_load(
                    (const i32x4*)(mrow + kt * 64 + n * 16 + g * 4));  // read-once
                u32x2 e;
                e.x = (mv.x ? 0xFFFFu : 0u) | (mv.y ? 0xFFFF0000u : 0u);
                e.y = (mv.z ? 0xFFFFu : 0u) | (mv.w ? 0xFFFF0000u : 0u);
                ob[(kt * 4 + n) * 64] = e;
            }
        }
    }
}

// ---- 128x128 bf16 MFMA GEMM, BK=64, B^T input, global_load_lds ----------
// (R4/R8-proven structure: single buffer, __syncthreads pair per K-tile.
//  R10's counted-vmcnt dbuf variant was correct but -15us: 64KB LDS halves
//  occupancy -- do not reintroduce.)
// MODE 0: fused QKV (Bt rows 0..3071; epilogue routes by region)
// MODE 3: O-proj (f32 out [M,E])
template <int MODE>
__global__ __launch_bounds__(256) void proj(const u16* __restrict__ A,
                                            const u16* __restrict__ Bt,
                                            const float* __restrict__ b0,
                                            const float* __restrict__ b1,
                                            const float* __restrict__ b2,
                                            u16* __restrict__ Qh, u16* __restrict__ Kh,
                                            u16* __restrict__ Vt,
                                            float* __restrict__ of) {
    __shared__ u16 sA[128 * 64], sB[128 * 64];  // linear (gload_lds fills lane-order)
    const int tid = threadIdx.x, lane = tid & 63, wid = tid >> 6;
    const int g = lane >> 4, lr = lane & 15;
    const int wr = wid >> 1, wc = wid & 1;
    constexpr int NCT = (MODE == 0) ? 24 : 8;
    const int nblk = (M_ / 128) * NCT;
    const int cpx = nblk / 8;
    const int sw = (blockIdx.x & 7) * cpx + (blockIdx.x >> 3);  // XCD-chunked
    const int rt = sw / NCT, ct = sw % NCT;
    const int row0 = rt * 128, col0 = ct * 128;

    // per-lane source row/col for staging (8 lanes x 16B = one 128B tile row)
    const int srow = lane >> 3;
    const int scol = (lane & 7) * 8;

    f32x4 acc[4][4] = {};
    for (int kt = 0; kt < E_ / 64; kt++) {
        int k0 = kt * 64;
        __syncthreads();  // previous tile fully consumed
#pragma unroll
        for (int j = 0; j < 4; j++) {
            int r = wid * 32 + j * 8;
            gl16(A  + (size_t)(row0 + r + srow) * E_ + k0 + scol, sA + r * 64);
            gl16(Bt + (size_t)(col0 + r + srow) * E_ + k0 + scol, sB + r * 64);
        }
        __syncthreads();  // drains vmcnt(0): tile visible
#pragma unroll
        for (int kk = 0; kk < 2; kk++) {
            s16x8 af[4], bfr[4];
#pragma unroll
            for (int m = 0; m < 4; m++)
                af[m] = *(const s16x8*)(sA + (wr * 64 + m * 16 + lr) * 64 + kk * 32 + g * 8);
#pragma unroll
            for (int n = 0; n < 4; n++)
                bfr[n] = *(const s16x8*)(sB + (wc * 64 + n * 16 + lr) * 64 + kk * 32 + g * 8);
            __builtin_amdgcn_s_setprio(1);
#pragma unroll
            for (int m = 0; m < 4; m++)
#pragma unroll
                for (int n = 0; n < 4; n++) mfma(acc[m][n], af[m], bfr[n]);
            __builtin_amdgcn_s_setprio(0);
        }
    }

    if constexpr (MODE == 3) {
#pragma unroll
        for (int n = 0; n < 4; n++) {
            int c = col0 + wc * 64 + n * 16 + lr;
            float bb = b0[c];
#pragma unroll
            for (int m = 0; m < 4; m++) {
                int rb = row0 + wr * 64 + m * 16 + g * 4;
#pragma unroll
                for (int i = 0; i < 4; i++) of[(size_t)(rb + i) * E_ + c] = acc[m][n][i] + bb;
            }
        }
    } else {
        const int region = col0 >> 10;  // block-uniform: 0=Q 1=K 2=V
        const float* bias = region == 0 ? b0 : (region == 1 ? b1 : b2);
        const float scl = region == 0 ? QSCALE : 1.0f;
        u16* dst = region == 0 ? Qh : Kh;
#pragma unroll
        for (int n = 0; n < 4; n++) {
            int ccol = (col0 & 1023) + wc * 64 + n * 16 + lr;  // 0..1023
            float bb = bias[ccol];
            int h = ccol >> 6, dh = ccol & 63;
#pragma unroll
            for (int m = 0; m < 4; m++) {
                int rb = row0 + wr * 64 + m * 16 + g * 4;
                int b = rb >> 11, s = rb & (S_ - 1);
                if (region == 2) {
                    u16x4 pk;
                    pk.x = f2bf(acc[m][n][0] + bb);
                    pk.y = f2bf(acc[m][n][1] + bb);
                    pk.z = f2bf(acc[m][n][2] + bb);
                    pk.w = f2bf(acc[m][n][3] + bb);
                    *(u16x4*)(Vt + ((size_t)((b * H_ + h) * DH + dh)) * S_ + s) = pk;
                } else {
#pragma unroll
                    for (int i = 0; i < 4; i++) {
                        int r = rb + i, bb2 = r >> 11, s2 = r & (S_ - 1);
                        dst[((size_t)((bb2 * H_ + h) * S_) + s2) * DH + dh] =
                            f2bf((acc[m][n][i] + bb) * scl);
                    }
                }
            }
        }
    }
}

// ---- flash attention (R8-green, structure FROZEN): swapped-operand -------
// grid 1024 flat (XCD-swizzled), 256 threads = 4 waves x 16 q-rows.
// Only change vs R8: mask loads are non-temporal (single-use stream; keeps
// the XCD-shared K/V panels resident in L2 -- targets the 34MB re-fetch).
__global__ __launch_bounds__(256, 4) void attn(const u16* __restrict__ Q,
                                               const u16* __restrict__ K,
                                               const u16* __restrict__ V,
                                               const u32x2* __restrict__ mc,
                                               u16* __restrict__ ctx) {
    __shared__ u16 sK[2][64 * 64];   // [kk][d], swizzled, double-buffered
    __shared__ u16 sV[2][64 * 64];   // [d][kk], swizzled, double-buffered
    __shared__ u16 sP[4][16 * 64];   // per-wave [q=lr][k], unit-swizzled
    const int tid = threadIdx.x, lane = tid & 63, wid = tid >> 6;
    const int g = lane >> 4, lr = lane & 15, swz = lr & 7;
    const int swg = (blockIdx.x & 7) * 128 + (blockIdx.x >> 3);
    const int q0 = (swg & 31) * 64, h = (swg >> 5) & 15, b = swg >> 9;
    const u16* qb = Q + ((size_t)(b * H_ + h) * S_ + q0) * DH;
    const u16* kb = K + (size_t)(b * H_ + h) * S_ * DH;
    const u16* vb = V + (size_t)(b * H_ + h) * DH * S_;
    const u32x2* mcb = mc + (size_t)(b * 128 + (q0 >> 4) + wid) * 32 * 4 * 64 + lane;
    u16* sPw = sP[wid];

    s16x8 qf[2];
#pragma unroll
    for (int dc = 0; dc < 2; dc++)
        qf[dc] = *(const s16x8*)(qb + (wid * 16 + lr) * DH + dc * 32 + g * 8);

    const u16 ov = (lr == 0) ? (u16)0x3F80 : (u16)0;
    s16x8 ones;
#pragma unroll
    for (int i = 0; i < 8; i++) ones[i] = (short)ov;

    f32x4 o[4] = {};
    f32x4 ol = {};  // ol[0] on lanes g==0 accumulates l(q=lr)
    float mrun = -3e38f;
    s16x8 kv[2], vv[2];
    u32x2 mmc[4], mmn[4];

#pragma unroll
    for (int p = 0; p < 2; p++) {
        int L = p * 256 + tid;
        kv[p] = *(const s16x8*)(kb + (L >> 3) * DH + (L & 7) * 8);
        vv[p] = *(const s16x8*)(vb + (L >> 3) * S_ + (L & 7) * 8);
    }
#pragma unroll
    for (int n = 0; n < 4; n++) mmc[n] = __builtin_nontemporal_load(&mcb[n * 64]);
#pragma unroll
    for (int p = 0; p < 2; p++) {
        int L = p * 256 + tid;
        int rr = L >> 3, cc = L & 7;
        *(s16x8*)(sK[0] + rr * 64 + (cc ^ (rr & 7)) * 8) = kv[p];
        *(s16x8*)(sV[0] + rr * 64 + (cc ^ (rr & 7)) * 8) = vv[p];
    }
    __syncthreads();

    int cur = 0;
    for (int kt = 0; kt < S_ / 64; kt++) {
        const int k0 = kt * 64;
        if (kt < S_ / 64 - 1) {
            const int kn = k0 + 64;
#pragma unroll
            for (int n = 0; n < 4; n++)
                mmn[n] = __builtin_nontemporal_load(&mcb[((kt + 1) * 4 + n) * 64]);
#pragma unroll
            for (int p = 0; p < 2; p++) {
                int L = p * 256 + tid;
                kv[p] = *(const s16x8*)(kb + (kn + (L >> 3)) * DH + (L & 7) * 8);
                vv[p] = *(const s16x8*)(vb + (L >> 3) * S_ + kn + (L & 7) * 8);
            }
        }

        const u16* sKc = sK[cur];
        const u16* sVc = sV[cur];
        f32x4 sc[4];
        __builtin_amdgcn_s_setprio(1);
#pragma unroll
        for (int n = 0; n < 4; n++) {
            const u16* kr = sKc + (n * 16 + lr) * 64;
            s16x8 kf0 = *(const s16x8*)(kr + (g ^ swz) * 8);
            s16x8 kf1 = *(const s16x8*)(kr + ((4 + g) ^ swz) * 8);
            f32x4 z = {0.f, 0.f, 0.f, 0.f};
            sc[n] = z;
            mfma(sc[n], kf0, qf[0]);
            mfma(sc[n], kf1, qf[1]);
        }
        __builtin_amdgcn_s_setprio(0);

        float t0 = max3f(sc[0][0], sc[0][1], sc[0][2]);
        float t1 = max3f(sc[0][3], sc[1][0], sc[1][1]);
        float t2 = max3f(sc[1][2], sc[1][3], sc[2][0]);
        float t3 = max3f(sc[2][1], sc[2][2], sc[2][3]);
        float t4 = max3f(sc[3][0], sc[3][1], sc[3][2]);
        float vm = fmaxf(max3f(max3f(t0, t1, sc[3][3]), t3, t4), t2);
        vm = fmaxf(vm, __shfl_xor(vm, 16));
        vm = fmaxf(vm, __shfl_xor(vm, 32));
        if (!__all(vm <= mrun + 8.f)) {  // defer-max (T13)
            float fac = __builtin_amdgcn_exp2f(mrun - vm);
            mrun = fmaxf(mrun, vm);
#pragma unroll
            for (int n = 0; n < 4; n++) o[n] *= fac;
            ol *= fac;
        }
#pragma unroll
        for (int n = 0; n < 4; n++) {
            u32x2 wp;
            wp.x = cvtpk(__builtin_amdgcn_exp2f(sc[n][0] - mrun),
                         __builtin_amdgcn_exp2f(sc[n][1] - mrun)) & mmc[n].x;
            wp.y = cvtpk(__builtin_amdgcn_exp2f(sc[n][2] - mrun),
                         __builtin_amdgcn_exp2f(sc[n][3] - mrun)) & mmc[n].y;
            int unit = (n * 2 + (g >> 1)) ^ swz;
            *(u32x2*)(sPw + lr * 64 + unit * 8 + (g & 1) * 4) = wp;
        }
        __builtin_amdgcn_s_setprio(1);
#pragma unroll
        for (int kc = 0; kc < 2; kc++) {
            s16x8 pb = *(const s16x8*)(sPw + lr * 64 + ((kc * 4 + g) ^ swz) * 8);
            mfma(ol, ones, pb);
#pragma unroll
            for (int n = 0; n < 4; n++) {
                int rv = n * 16 + lr;
                s16x8 vf = *(const s16x8*)(sVc + rv * 64 + ((kc * 4 + g) ^ (rv & 7)) * 8);
                mfma(o[n], vf, pb);
            }
        }
        __builtin_amdgcn_s_setprio(0);
        if (kt < S_ / 64 - 1) {
#pragma unroll
            for (int p = 0; p < 2; p++) {
                int L = p * 256 + tid;
                int rr = L >> 3, cc = L & 7;
                *(s16x8*)(sK[cur ^ 1] + rr * 64 + (cc ^ (rr & 7)) * 8) = kv[p];
                *(s16x8*)(sV[cur ^ 1] + rr * 64 + (cc ^ (rr & 7)) * 8) = vv[p];
            }
#pragma unroll
            for (int n = 0; n < 4; n++) mmc[n] = mmn[n];
            __syncthreads();
            cur ^= 1;
        }
    }
    {
        float lsum = __shfl(ol[0], lr);  // lane lr holds l(q=lr)
        float inv = 1.f / lsum;
#pragma unroll
        for (int n = 0; n < 4; n++) {
            u16x4 pk;
#pragma unroll
            for (int i = 0; i < 4; i++) pk[i] = f2bf(o[n][i] * inv);
            *(u16x4*)(sPw + lr * 64 + n * 16 + g * 4) = pk;
        }
#pragma unroll
        for (int half = 0; half < 2; half++) {
            int rr = half * 8 + (lane >> 3);
            s16x8 v = *(const s16x8*)(sPw + rr * 64 + (lane & 7) * 8);
            int q = q0 + wid * 16 + rr;
            *(s16x8*)(ctx + ((size_t)(b * S_ + q)) * E_ + h * DH + (lane & 7) * 8) = v;
        }
    }
}

// ---- launch -------------------------------------------------------------

extern "C" void kernel_launch(void* const* d_in, const int* in_sizes, int n_in,
                              void* d_out, int out_size, void* d_ws, size_t ws_size,
                              hipStream_t stream) {
    const float* x  = (const float*)d_in[0];
    const int* mask = (const int*)d_in[1];
    const float* Wq = (const float*)d_in[2]; const float* bq = (const float*)d_in[3];
    const float* Wk = (const float*)d_in[4]; const float* bk = (const float*)d_in[5];
    const float* Wv = (const float*)d_in[6]; const float* bv = (const float*)d_in[7];
    const float* Wo = (const float*)d_in[8]; const float* bo = (const float*)d_in[9];
    float* out = (float*)d_out;

    char* ws = (char*)d_ws;
    u16* xb     = (u16*)(ws);                      // 8 MB  [M,E] bf16
    u16* Wqkvt  = (u16*)(ws + (8u  << 20));        // 6 MB  [3072,1024] fused B^T
    u16* Wot    = (u16*)(ws + (14u << 20));        // 2 MB
    u16* Qh     = (u16*)(ws + (16u << 20));        // 8 MB  [B,H,S,64] (pre-scaled)
    u16* Kh     = (u16*)(ws + (24u << 20));        // 8 MB  [B,H,S,64]
    u16* Vt     = (u16*)(ws + (32u << 20));        // 8 MB  [B,H,64,S]
    u16* ctx    = (u16*)(ws + (40u << 20));        // 8 MB  [M,E]
    u32x2* mc   = (u32x2*)(ws + (48u << 20));      // 16 MB coalesced AND-masks

    prep<<<5376, 256, 0, stream>>>(x, xb, Wq, Wk, Wv, Wo, Wqkvt, Wot, mask, mc);

    proj<0><<<(M_ / 128) * (3072 / 128), 256, 0, stream>>>(xb, Wqkvt, bq, bk, bv,
                                                           Qh, Kh, Vt, nullptr);

    attn<<<(S_ / 64) * H_ * B_, 256, 0, stream>>>(Qh, Kh, Vt, mc, ctx);

    proj<3><<<(M_ / 128) * (E_ / 128), 256, 0, stream>>>(ctx, Wot, bo, nullptr, nullptr,
                                                         nullptr, nullptr, nullptr, out);
}

// Round 13
// 150.692 us; speedup vs baseline: 1.1709x; 1.1709x over previous
//
#include <hip/hip_runtime.h>

typedef float f32x4 __attribute__((ext_vector_type(4)));
typedef short s16x8 __attribute__((ext_vector_type(8)));
typedef unsigned short u16;
typedef unsigned short u16x4 __attribute__((ext_vector_type(4)));
typedef unsigned int u32x2 __attribute__((ext_vector_type(2)));

#define DI __device__ __forceinline__

constexpr int B_ = 2, S_ = 2048, E_ = 1024, H_ = 16, DH = 64, M_ = B_ * S_;
// 1/sqrt(64) * log2(e): scores land in log2 domain -> exp2 for softmax
constexpr float QSCALE = 0.125f * 1.4426950408889634f;

DI u16 f2bf(float f) {
    unsigned u = __float_as_uint(f);
    u += 0x7fffu + ((u >> 16) & 1u);
    return (u16)(u >> 16);
}

DI unsigned cvtpk(float lo, float hi) {
    unsigned r;
    asm("v_cvt_pk_bf16_f32 %0, %1, %2" : "=v"(r) : "v"(lo), "v"(hi));
    return r;
}

DI float max3f(float a, float b, float c) {
    float r;
    asm("v_max3_f32 %0, %1, %2, %3" : "=v"(r) : "v"(a), "v"(b), "v"(c));
    return r;
}

DI void mfma(f32x4& d, s16x8 a, s16x8 b) {
    asm("v_mfma_f32_16x16x32_bf16 %0, %1, %2, %0" : "+v"(d) : "v"(a), "v"(b));
}

// expand 16 mask bits (bit n*4+i for score sc[n][i]) into AND-words:
// mm[n].x = lo:bit(4n+0) hi:bit(4n+1), mm[n].y = lo:bit(4n+2) hi:bit(4n+3)
DI void mexp16(unsigned bits, u32x2* mm) {
#pragma unroll
    for (int n = 0; n < 4; n++) {
        unsigned e0 = (unsigned)(-(int)((bits >> (4 * n + 0)) & 1u));
        unsigned e1 = (unsigned)(-(int)((bits >> (4 * n + 1)) & 1u));
        unsigned e2 = (unsigned)(-(int)((bits >> (4 * n + 2)) & 1u));
        unsigned e3 = (unsigned)(-(int)((bits >> (4 * n + 3)) & 1u));
        mm[n].x = (e0 & 0xFFFFu) | (e1 & 0xFFFF0000u);
        mm[n].y = (e2 & 0xFFFFu) | (e3 & 0xFFFF0000u);
    }
}

typedef __attribute__((address_space(1))) const void gas_cv;
typedef __attribute__((address_space(3))) void las_v;
// async global->LDS, 16B per lane; l must be wave-uniform (HW adds lane*16)
DI void gl16(const void* g, void* l) {
    __builtin_amdgcn_global_load_lds((gas_cv*)g, (las_v*)l, 16, 0, 0);
}

// ---- fused preprocess: cvt_bf16 | wtrans x4 | mask bit-pack -------------
// blocks [0,4096): x->bf16.  [4096,5120): weight transpose (256 blocks per
// weight).  [5120,5376): mask -> per-lane bit-packed u16 words.
__global__ __launch_bounds__(256) void prep(const float* __restrict__ x,
                                            u16* __restrict__ xb,
                                            const float* __restrict__ Wq,
                                            const float* __restrict__ Wk,
                                            const float* __restrict__ Wv,
                                            const float* __restrict__ Wo,
                                            u16* __restrict__ Wqkvt,
                                            u16* __restrict__ Wot,
                                            const int* __restrict__ mask,
                                            u16* __restrict__ mb) {
    __shared__ float t[64][65];
    const int bid = blockIdx.x;
    if (bid < 4096) {
        int i = bid * 256 + threadIdx.x;
        float4 v = ((const float4*)x)[i];
        u16x4 o;
        o.x = f2bf(v.x); o.y = f2bf(v.y); o.z = f2bf(v.z); o.w = f2bf(v.w);
        ((u16x4*)xb)[i] = o;
    } else if (bid < 5120) {
        const int wb = bid - 4096, w = wb >> 8, rem = wb & 255;
        const float* in = (w == 0) ? Wq : (w == 1) ? Wk : (w == 2) ? Wv : Wo;
        u16* out = (w == 3) ? Wot : Wqkvt + w * 1024 * 1024;
        const int k0 = (rem & 15) * 64, n0 = (rem >> 4) * 64;
        const int tx = threadIdx.x & 63, ty = threadIdx.x >> 6;
#pragma unroll
        for (int i = 0; i < 16; i++) {
            int r = i * 4 + ty;
            t[r][tx] = in[(k0 + r) * E_ + n0 + tx];
        }
        __syncthreads();
#pragma unroll
        for (int i = 0; i < 16; i++) {
            int r = i * 4 + ty;
            out[(n0 + r) * E_ + k0 + tx] = f2bf(t[tx][r]);
        }
    } else {
        // mb[b][qt=q>>4][kt=k>>6][lane(g*16+lr)] : u16, bit n*4+i =
        // mask[b][q=qt*16+lr][k=kt*64+n*16+g*4+i]  (1 MB total, L2-resident)
        const int bq = bid - 5120;             // b*128 + qt
        const int b = bq >> 7, qt = bq & 127;
        const int tid = threadIdx.x, lane = tid & 63, w = tid >> 6;
        const int lr = lane & 15, g = lane >> 4;
        const int* mrow = mask + ((size_t)(b * S_ + qt * 16 + lr)) * S_;
        u16* ob = mb + (size_t)bq * 2048 + lane;
        for (int kt = w; kt < 32; kt += 4) {
            unsigned bits = 0;
#pragma unroll
            for (int n = 0; n < 4; n++) {
                int4 mv = *(const int4*)(mrow + kt * 64 + n * 16 + g * 4);
                bits |= (mv.x != 0 ? 1u : 0u) << (4 * n + 0);
                bits |= (mv.y != 0 ? 1u : 0u) << (4 * n + 1);
                bits |= (mv.z != 0 ? 1u : 0u) << (4 * n + 2);
                bits |= (mv.w != 0 ? 1u : 0u) << (4 * n + 3);
            }
            ob[kt * 64] = (u16)bits;
        }
    }
}

// ---- 128x128 bf16 MFMA GEMM, BK=64, B^T input, global_load_lds ----------
// (R4/R8-proven structure: single buffer, __syncthreads pair per K-tile.
//  R10's counted-vmcnt dbuf variant was correct but -15us: 64KB LDS halves
//  occupancy -- do not reintroduce.)
// MODE 0: fused QKV (Bt rows 0..3071; epilogue routes by region)
// MODE 3: O-proj (f32 out [M,E])
template <int MODE>
__global__ __launch_bounds__(256) void proj(const u16* __restrict__ A,
                                            const u16* __restrict__ Bt,
                                            const float* __restrict__ b0,
                                            const float* __restrict__ b1,
                                            const float* __restrict__ b2,
                                            u16* __restrict__ Qh, u16* __restrict__ Kh,
                                            u16* __restrict__ Vt,
                                            float* __restrict__ of) {
    __shared__ u16 sA[128 * 64], sB[128 * 64];  // linear (gload_lds fills lane-order)
    const int tid = threadIdx.x, lane = tid & 63, wid = tid >> 6;
    const int g = lane >> 4, lr = lane & 15;
    const int wr = wid >> 1, wc = wid & 1;
    constexpr int NCT = (MODE == 0) ? 24 : 8;
    const int nblk = (M_ / 128) * NCT;
    const int cpx = nblk / 8;
    const int sw = (blockIdx.x & 7) * cpx + (blockIdx.x >> 3);  // XCD-chunked
    const int rt = sw / NCT, ct = sw % NCT;
    const int row0 = rt * 128, col0 = ct * 128;

    // per-lane source row/col for staging (8 lanes x 16B = one 128B tile row)
    const int srow = lane >> 3;
    const int scol = (lane & 7) * 8;

    f32x4 acc[4][4] = {};
    for (int kt = 0; kt < E_ / 64; kt++) {
        int k0 = kt * 64;
        __syncthreads();  // previous tile fully consumed
#pragma unroll
        for (int j = 0; j < 4; j++) {
            int r = wid * 32 + j * 8;
            gl16(A  + (size_t)(row0 + r + srow) * E_ + k0 + scol, sA + r * 64);
            gl16(Bt + (size_t)(col0 + r + srow) * E_ + k0 + scol, sB + r * 64);
        }
        __syncthreads();  // drains vmcnt(0): tile visible
#pragma unroll
        for (int kk = 0; kk < 2; kk++) {
            s16x8 af[4], bfr[4];
#pragma unroll
            for (int m = 0; m < 4; m++)
                af[m] = *(const s16x8*)(sA + (wr * 64 + m * 16 + lr) * 64 + kk * 32 + g * 8);
#pragma unroll
            for (int n = 0; n < 4; n++)
                bfr[n] = *(const s16x8*)(sB + (wc * 64 + n * 16 + lr) * 64 + kk * 32 + g * 8);
            __builtin_amdgcn_s_setprio(1);
#pragma unroll
            for (int m = 0; m < 4; m++)
#pragma unroll
                for (int n = 0; n < 4; n++) mfma(acc[m][n], af[m], bfr[n]);
            __builtin_amdgcn_s_setprio(0);
        }
    }

    if constexpr (MODE == 3) {
#pragma unroll
        for (int n = 0; n < 4; n++) {
            int c = col0 + wc * 64 + n * 16 + lr;
            float bb = b0[c];
#pragma unroll
            for (int m = 0; m < 4; m++) {
                int rb = row0 + wr * 64 + m * 16 + g * 4;
#pragma unroll
                for (int i = 0; i < 4; i++) of[(size_t)(rb + i) * E_ + c] = acc[m][n][i] + bb;
            }
        }
    } else {
        const int region = col0 >> 10;  // block-uniform: 0=Q 1=K 2=V
        const float* bias = region == 0 ? b0 : (region == 1 ? b1 : b2);
        const float scl = region == 0 ? QSCALE : 1.0f;
        u16* dst = region == 0 ? Qh : Kh;
#pragma unroll
        for (int n = 0; n < 4; n++) {
            int ccol = (col0 & 1023) + wc * 64 + n * 16 + lr;  // 0..1023
            float bb = bias[ccol];
            int h = ccol >> 6, dh = ccol & 63;
#pragma unroll
            for (int m = 0; m < 4; m++) {
                int rb = row0 + wr * 64 + m * 16 + g * 4;
                int b = rb >> 11, s = rb & (S_ - 1);
                if (region == 2) {
                    u16x4 pk;
                    pk.x = f2bf(acc[m][n][0] + bb);
                    pk.y = f2bf(acc[m][n][1] + bb);
                    pk.z = f2bf(acc[m][n][2] + bb);
                    pk.w = f2bf(acc[m][n][3] + bb);
                    *(u16x4*)(Vt + ((size_t)((b * H_ + h) * DH + dh)) * S_ + s) = pk;
                } else {
#pragma unroll
                    for (int i = 0; i < 4; i++) {
                        int r = rb + i, bb2 = r >> 11, s2 = r & (S_ - 1);
                        dst[((size_t)((bb2 * H_ + h) * S_) + s2) * DH + dh] =
                            f2bf((acc[m][n][i] + bb) * scl);
                    }
                }
            }
        }
    }
}

// ---- flash attention (R8-green, structure FROZEN): swapped-operand -------
// grid 1024 flat (XCD-swizzled), 256 threads = 4 waves x 16 q-rows.
// Only change vs R8: mask comes from the 1 MB bit-packed array (one u16
// per lane per tile, L2-resident with free 16x head reuse), expanded to
// the same AND-words in registers (~48 VALU/tile).
__global__ __launch_bounds__(256, 4) void attn(const u16* __restrict__ Q,
                                               const u16* __restrict__ K,
                                               const u16* __restrict__ V,
                                               const u16* __restrict__ mb,
                                               u16* __restrict__ ctx) {
    __shared__ u16 sK[2][64 * 64];   // [kk][d], swizzled, double-buffered
    __shared__ u16 sV[2][64 * 64];   // [d][kk], swizzled, double-buffered
    __shared__ u16 sP[4][16 * 64];   // per-wave [q=lr][k], unit-swizzled
    const int tid = threadIdx.x, lane = tid & 63, wid = tid >> 6;
    const int g = lane >> 4, lr = lane & 15, swz = lr & 7;
    const int swg = (blockIdx.x & 7) * 128 + (blockIdx.x >> 3);
    const int q0 = (swg & 31) * 64, h = (swg >> 5) & 15, b = swg >> 9;
    const u16* qb = Q + ((size_t)(b * H_ + h) * S_ + q0) * DH;
    const u16* kb = K + (size_t)(b * H_ + h) * S_ * DH;
    const u16* vb = V + (size_t)(b * H_ + h) * DH * S_;
    // bit-packed mask base for this wave: mb[b][qt][kt][lane]
    const u16* mbb = mb + (size_t)(b * 128 + (q0 >> 4) + wid) * 2048 + lane;
    u16* sPw = sP[wid];

    s16x8 qf[2];
#pragma unroll
    for (int dc = 0; dc < 2; dc++)
        qf[dc] = *(const s16x8*)(qb + (wid * 16 + lr) * DH + dc * 32 + g * 8);

    const u16 ov = (lr == 0) ? (u16)0x3F80 : (u16)0;
    s16x8 ones;
#pragma unroll
    for (int i = 0; i < 8; i++) ones[i] = (short)ov;

    f32x4 o[4] = {};
    f32x4 ol = {};  // ol[0] on lanes g==0 accumulates l(q=lr)
    float mrun = -3e38f;
    s16x8 kv[2], vv[2];
    u32x2 mmc[4];
    unsigned bitn = 0;

#pragma unroll
    for (int p = 0; p < 2; p++) {
        int L = p * 256 + tid;
        kv[p] = *(const s16x8*)(kb + (L >> 3) * DH + (L & 7) * 8);
        vv[p] = *(const s16x8*)(vb + (L >> 3) * S_ + (L & 7) * 8);
    }
    mexp16(mbb[0], mmc);
#pragma unroll
    for (int p = 0; p < 2; p++) {
        int L = p * 256 + tid;
        int rr = L >> 3, cc = L & 7;
        *(s16x8*)(sK[0] + rr * 64 + (cc ^ (rr & 7)) * 8) = kv[p];
        *(s16x8*)(sV[0] + rr * 64 + (cc ^ (rr & 7)) * 8) = vv[p];
    }
    __syncthreads();

    int cur = 0;
    for (int kt = 0; kt < S_ / 64; kt++) {
        const int k0 = kt * 64;
        if (kt < S_ / 64 - 1) {
            const int kn = k0 + 64;
            bitn = mbb[(kt + 1) * 64];
#pragma unroll
            for (int p = 0; p < 2; p++) {
                int L = p * 256 + tid;
                kv[p] = *(const s16x8*)(kb + (kn + (L >> 3)) * DH + (L & 7) * 8);
                vv[p] = *(const s16x8*)(vb + (L >> 3) * S_ + kn + (L & 7) * 8);
            }
        }

        const u16* sKc = sK[cur];
        const u16* sVc = sV[cur];
        f32x4 sc[4];
        __builtin_amdgcn_s_setprio(1);
#pragma unroll
        for (int n = 0; n < 4; n++) {
            const u16* kr = sKc + (n * 16 + lr) * 64;
            s16x8 kf0 = *(const s16x8*)(kr + (g ^ swz) * 8);
            s16x8 kf1 = *(const s16x8*)(kr + ((4 + g) ^ swz) * 8);
            f32x4 z = {0.f, 0.f, 0.f, 0.f};
            sc[n] = z;
            mfma(sc[n], kf0, qf[0]);
            mfma(sc[n], kf1, qf[1]);
        }
        __builtin_amdgcn_s_setprio(0);

        float t0 = max3f(sc[0][0], sc[0][1], sc[0][2]);
        float t1 = max3f(sc[0][3], sc[1][0], sc[1][1]);
        float t2 = max3f(sc[1][2], sc[1][3], sc[2][0]);
        float t3 = max3f(sc[2][1], sc[2][2], sc[2][3]);
        float t4 = max3f(sc[3][0], sc[3][1], sc[3][2]);
        float vm = fmaxf(max3f(max3f(t0, t1, sc[3][3]), t3, t4), t2);
        vm = fmaxf(vm, __shfl_xor(vm, 16));
        vm = fmaxf(vm, __shfl_xor(vm, 32));
        if (!__all(vm <= mrun + 8.f)) {  // defer-max (T13)
            float fac = __builtin_amdgcn_exp2f(mrun - vm);
            mrun = fmaxf(mrun, vm);
#pragma unroll
            for (int n = 0; n < 4; n++) o[n] *= fac;
            ol *= fac;
        }
#pragma unroll
        for (int n = 0; n < 4; n++) {
            u32x2 wp;
            wp.x = cvtpk(__builtin_amdgcn_exp2f(sc[n][0] - mrun),
                         __builtin_amdgcn_exp2f(sc[n][1] - mrun)) & mmc[n].x;
            wp.y = cvtpk(__builtin_amdgcn_exp2f(sc[n][2] - mrun),
                         __builtin_amdgcn_exp2f(sc[n][3] - mrun)) & mmc[n].y;
            int unit = (n * 2 + (g >> 1)) ^ swz;
            *(u32x2*)(sPw + lr * 64 + unit * 8 + (g & 1) * 4) = wp;
        }
        __builtin_amdgcn_s_setprio(1);
#pragma unroll
        for (int kc = 0; kc < 2; kc++) {
            s16x8 pb = *(const s16x8*)(sPw + lr * 64 + ((kc * 4 + g) ^ swz) * 8);
            mfma(ol, ones, pb);
#pragma unroll
            for (int n = 0; n < 4; n++) {
                int rv = n * 16 + lr;
                s16x8 vf = *(const s16x8*)(sVc + rv * 64 + ((kc * 4 + g) ^ (rv & 7)) * 8);
                mfma(o[n], vf, pb);
            }
        }
        __builtin_amdgcn_s_setprio(0);
        if (kt < S_ / 64 - 1) {
#pragma unroll
            for (int p = 0; p < 2; p++) {
                int L = p * 256 + tid;
                int rr = L >> 3, cc = L & 7;
                *(s16x8*)(sK[cur ^ 1] + rr * 64 + (cc ^ (rr & 7)) * 8) = kv[p];
                *(s16x8*)(sV[cur ^ 1] + rr * 64 + (cc ^ (rr & 7)) * 8) = vv[p];
            }
            mexp16(bitn, mmc);  // expand prefetched bits for next tile
            __syncthreads();
            cur ^= 1;
        }
    }
    {
        float lsum = __shfl(ol[0], lr);  // lane lr holds l(q=lr)
        float inv = 1.f / lsum;
#pragma unroll
        for (int n = 0; n < 4; n++) {
            u16x4 pk;
#pragma unroll
            for (int i = 0; i < 4; i++) pk[i] = f2bf(o[n][i] * inv);
            *(u16x4*)(sPw + lr * 64 + n * 16 + g * 4) = pk;
        }
#pragma unroll
        for (int half = 0; half < 2; half++) {
            int rr = half * 8 + (lane >> 3);
            s16x8 v = *(const s16x8*)(sPw + rr * 64 + (lane & 7) * 8);
            int q = q0 + wid * 16 + rr;
            *(s16x8*)(ctx + ((size_t)(b * S_ + q)) * E_ + h * DH + (lane & 7) * 8) = v;
        }
    }
}

// ---- launch -------------------------------------------------------------

extern "C" void kernel_launch(void* const* d_in, const int* in_sizes, int n_in,
                              void* d_out, int out_size, void* d_ws, size_t ws_size,
                              hipStream_t stream) {
    const float* x  = (const float*)d_in[0];
    const int* mask = (const int*)d_in[1];
    const float* Wq = (const float*)d_in[2]; const float* bq = (const float*)d_in[3];
    const float* Wk = (const float*)d_in[4]; const float* bk = (const float*)d_in[5];
    const float* Wv = (const float*)d_in[6]; const float* bv = (const float*)d_in[7];
    const float* Wo = (const float*)d_in[8]; const float* bo = (const float*)d_in[9];
    float* out = (float*)d_out;

    char* ws = (char*)d_ws;
    u16* xb     = (u16*)(ws);                      // 8 MB  [M,E] bf16
    u16* Wqkvt  = (u16*)(ws + (8u  << 20));        // 6 MB  [3072,1024] fused B^T
    u16* Wot    = (u16*)(ws + (14u << 20));        // 2 MB
    u16* Qh     = (u16*)(ws + (16u << 20));        // 8 MB  [B,H,S,64] (pre-scaled)
    u16* Kh     = (u16*)(ws + (24u << 20));        // 8 MB  [B,H,S,64]
    u16* Vt     = (u16*)(ws + (32u << 20));        // 8 MB  [B,H,64,S]
    u16* ctx    = (u16*)(ws + (40u << 20));        // 8 MB  [M,E]
    u16* mb     = (u16*)(ws + (48u << 20));        // 1 MB  bit-packed masks

    prep<<<5376, 256, 0, stream>>>(x, xb, Wq, Wk, Wv, Wo, Wqkvt, Wot, mask, mb);

    proj<0><<<(M_ / 128) * (3072 / 128), 256, 0, stream>>>(xb, Wqkvt, bq, bk, bv,
                                                           Qh, Kh, Vt, nullptr);

    attn<<<(S_ / 64) * H_ * B_, 256, 0, stream>>>(Qh, Kh, Vt, mb, ctx);

    proj<3><<<(M_ / 128) * (E_ / 128), 256, 0, stream>>>(ctx, Wot, bo, nullptr, nullptr,
                                                         nullptr, nullptr, nullptr, out);
}

// Round 14
// 137.339 us; speedup vs baseline: 1.2847x; 1.0972x over previous
//
#include <hip/hip_runtime.h>

typedef float f32x4 __attribute__((ext_vector_type(4)));
typedef short s16x8 __attribute__((ext_vector_type(8)));
typedef unsigned short u16;
typedef unsigned short u16x4 __attribute__((ext_vector_type(4)));
typedef unsigned int u32x2 __attribute__((ext_vector_type(2)));

#define DI __device__ __forceinline__

constexpr int B_ = 2, S_ = 2048, E_ = 1024, H_ = 16, DH = 64, M_ = B_ * S_;
// 1/sqrt(64) * log2(e): scores land in log2 domain -> exp2 for softmax
constexpr float QSCALE = 0.125f * 1.4426950408889634f;

DI u16 f2bf(float f) {
    unsigned u = __float_as_uint(f);
    u += 0x7fffu + ((u >> 16) & 1u);
    return (u16)(u >> 16);
}

DI unsigned cvtpk(float lo, float hi) {
    unsigned r;
    asm("v_cvt_pk_bf16_f32 %0, %1, %2" : "=v"(r) : "v"(lo), "v"(hi));
    return r;
}

DI float max3f(float a, float b, float c) {
    float r;
    asm("v_max3_f32 %0, %1, %2, %3" : "=v"(r) : "v"(a), "v"(b), "v"(c));
    return r;
}

DI void mfma(f32x4& d, s16x8 a, s16x8 b) {
    asm("v_mfma_f32_16x16x32_bf16 %0, %1, %2, %0" : "+v"(d) : "v"(a), "v"(b));
}

// expand 16 mask bits (bit n*4+i for score sc[n][i]) into AND-words:
// mm[n].x = lo:bit(4n+0) hi:bit(4n+1), mm[n].y = lo:bit(4n+2) hi:bit(4n+3)
DI void mexp16(unsigned bits, u32x2* mm) {
#pragma unroll
    for (int n = 0; n < 4; n++) {
        unsigned e0 = (unsigned)(-(int)((bits >> (4 * n + 0)) & 1u));
        unsigned e1 = (unsigned)(-(int)((bits >> (4 * n + 1)) & 1u));
        unsigned e2 = (unsigned)(-(int)((bits >> (4 * n + 2)) & 1u));
        unsigned e3 = (unsigned)(-(int)((bits >> (4 * n + 3)) & 1u));
        mm[n].x = (e0 & 0xFFFFu) | (e1 & 0xFFFF0000u);
        mm[n].y = (e2 & 0xFFFFu) | (e3 & 0xFFFF0000u);
    }
}

typedef __attribute__((address_space(1))) const void gas_cv;
typedef __attribute__((address_space(3))) void las_v;
// async global->LDS, 16B per lane; l must be wave-uniform (HW adds lane*16)
DI void gl16(const void* g, void* l) {
    __builtin_amdgcn_global_load_lds((gas_cv*)g, (las_v*)l, 16, 0, 0);
}

// ---- fused preprocess: cvt_bf16 | wtrans x4 ------------------------------
// blocks [0,4096): x->bf16.  [4096,5120): weight transpose (256 blocks per
// weight).  (mask bit-pack moved into proj<0>'s tail blocks -- it has no
// dependency on prep outputs and hides under proj0's compute.)
__global__ __launch_bounds__(256) void prep(const float* __restrict__ x,
                                            u16* __restrict__ xb,
                                            const float* __restrict__ Wq,
                                            const float* __restrict__ Wk,
                                            const float* __restrict__ Wv,
                                            const float* __restrict__ Wo,
                                            u16* __restrict__ Wqkvt,
                                            u16* __restrict__ Wot) {
    __shared__ float t[64][65];
    const int bid = blockIdx.x;
    if (bid < 4096) {
        int i = bid * 256 + threadIdx.x;
        float4 v = ((const float4*)x)[i];
        u16x4 o;
        o.x = f2bf(v.x); o.y = f2bf(v.y); o.z = f2bf(v.z); o.w = f2bf(v.w);
        ((u16x4*)xb)[i] = o;
    } else {
        const int wb = bid - 4096, w = wb >> 8, rem = wb & 255;
        const float* in = (w == 0) ? Wq : (w == 1) ? Wk : (w == 2) ? Wv : Wo;
        u16* out = (w == 3) ? Wot : Wqkvt + w * 1024 * 1024;
        const int k0 = (rem & 15) * 64, n0 = (rem >> 4) * 64;
        const int tx = threadIdx.x & 63, ty = threadIdx.x >> 6;
#pragma unroll
        for (int i = 0; i < 16; i++) {
            int r = i * 4 + ty;
            t[r][tx] = in[(k0 + r) * E_ + n0 + tx];
        }
        __syncthreads();
#pragma unroll
        for (int i = 0; i < 16; i++) {
            int r = i * 4 + ty;
            out[(n0 + r) * E_ + k0 + tx] = f2bf(t[tx][r]);
        }
    }
}

// ---- 128x128 bf16 MFMA GEMM, BK=64, B^T input, global_load_lds ----------
// (R4/R8-proven structure: single buffer, __syncthreads pair per K-tile.
//  R10's counted-vmcnt dbuf variant was correct but -15us: 64KB LDS halves
//  occupancy -- do not reintroduce.)
// MODE 0: fused QKV (768 compute blocks) + mask bit-pack tail blocks
//         [768,1024) that overlap with compute (no shared deps).
// MODE 3: O-proj (f32 out [M,E])
template <int MODE>
__global__ __launch_bounds__(256) void proj(const u16* __restrict__ A,
                                            const u16* __restrict__ Bt,
                                            const float* __restrict__ b0,
                                            const float* __restrict__ b1,
                                            const float* __restrict__ b2,
                                            u16* __restrict__ Qh, u16* __restrict__ Kh,
                                            u16* __restrict__ Vt,
                                            float* __restrict__ of,
                                            const int* __restrict__ mask,
                                            u16* __restrict__ mb) {
    __shared__ u16 sA[128 * 64], sB[128 * 64];  // linear (gload_lds fills lane-order)
    constexpr int NCT = (MODE == 0) ? 24 : 8;
    constexpr int nblk = (M_ / 128) * NCT;

    if constexpr (MODE == 0) {
        if (blockIdx.x >= nblk) {
            // ---- mask bit-pack (moved from prep; runs in proj0's tail) ----
            // mb[b][qt=q>>4][kt=k>>6][lane(g*16+lr)] : u16, bit n*4+i =
            // mask[b][q=qt*16+lr][k=kt*64+n*16+g*4+i] (1 MB, L2-resident)
            const int bq = blockIdx.x - nblk;      // b*128 + qt
            const int b = bq >> 7, qt = bq & 127;
            const int tid = threadIdx.x, lane = tid & 63, w = tid >> 6;
            const int lr = lane & 15, g = lane >> 4;
            const int* mrow = mask + ((size_t)(b * S_ + qt * 16 + lr)) * S_;
            u16* ob = mb + (size_t)bq * 2048 + lane;
            for (int kt = w; kt < 32; kt += 4) {
                unsigned bits = 0;
#pragma unroll
                for (int n = 0; n < 4; n++) {
                    int4 mv = *(const int4*)(mrow + kt * 64 + n * 16 + g * 4);
                    bits |= (mv.x != 0 ? 1u : 0u) << (4 * n + 0);
                    bits |= (mv.y != 0 ? 1u : 0u) << (4 * n + 1);
                    bits |= (mv.z != 0 ? 1u : 0u) << (4 * n + 2);
                    bits |= (mv.w != 0 ? 1u : 0u) << (4 * n + 3);
                }
                ob[kt * 64] = (u16)bits;
            }
            return;
        }
    }

    const int tid = threadIdx.x, lane = tid & 63, wid = tid >> 6;
    const int g = lane >> 4, lr = lane & 15;
    const int wr = wid >> 1, wc = wid & 1;
    const int cpx = nblk / 8;
    const int sw = (blockIdx.x & 7) * cpx + (blockIdx.x >> 3);  // XCD-chunked
    const int rt = sw / NCT, ct = sw % NCT;
    const int row0 = rt * 128, col0 = ct * 128;

    // per-lane source row/col for staging (8 lanes x 16B = one 128B tile row)
    const int srow = lane >> 3;
    const int scol = (lane & 7) * 8;

    f32x4 acc[4][4] = {};
    for (int kt = 0; kt < E_ / 64; kt++) {
        int k0 = kt * 64;
        __syncthreads();  // previous tile fully consumed
#pragma unroll
        for (int j = 0; j < 4; j++) {
            int r = wid * 32 + j * 8;
            gl16(A  + (size_t)(row0 + r + srow) * E_ + k0 + scol, sA + r * 64);
            gl16(Bt + (size_t)(col0 + r + srow) * E_ + k0 + scol, sB + r * 64);
        }
        __syncthreads();  // drains vmcnt(0): tile visible
#pragma unroll
        for (int kk = 0; kk < 2; kk++) {
            s16x8 af[4], bfr[4];
#pragma unroll
            for (int m = 0; m < 4; m++)
                af[m] = *(const s16x8*)(sA + (wr * 64 + m * 16 + lr) * 64 + kk * 32 + g * 8);
#pragma unroll
            for (int n = 0; n < 4; n++)
                bfr[n] = *(const s16x8*)(sB + (wc * 64 + n * 16 + lr) * 64 + kk * 32 + g * 8);
            __builtin_amdgcn_s_setprio(1);
#pragma unroll
            for (int m = 0; m < 4; m++)
#pragma unroll
                for (int n = 0; n < 4; n++) mfma(acc[m][n], af[m], bfr[n]);
            __builtin_amdgcn_s_setprio(0);
        }
    }

    if constexpr (MODE == 3) {
#pragma unroll
        for (int n = 0; n < 4; n++) {
            int c = col0 + wc * 64 + n * 16 + lr;
            float bb = b0[c];
#pragma unroll
            for (int m = 0; m < 4; m++) {
                int rb = row0 + wr * 64 + m * 16 + g * 4;
#pragma unroll
                for (int i = 0; i < 4; i++) of[(size_t)(rb + i) * E_ + c] = acc[m][n][i] + bb;
            }
        }
    } else {
        const int region = col0 >> 10;  // block-uniform: 0=Q 1=K 2=V
        const float* bias = region == 0 ? b0 : (region == 1 ? b1 : b2);
        const float scl = region == 0 ? QSCALE : 1.0f;
        u16* dst = region == 0 ? Qh : Kh;
#pragma unroll
        for (int n = 0; n < 4; n++) {
            int ccol = (col0 & 1023) + wc * 64 + n * 16 + lr;  // 0..1023
            float bb = bias[ccol];
            int h = ccol >> 6, dh = ccol & 63;
#pragma unroll
            for (int m = 0; m < 4; m++) {
                int rb = row0 + wr * 64 + m * 16 + g * 4;
                int b = rb >> 11, s = rb & (S_ - 1);
                if (region == 2) {
                    u16x4 pk;
                    pk.x = f2bf(acc[m][n][0] + bb);
                    pk.y = f2bf(acc[m][n][1] + bb);
                    pk.z = f2bf(acc[m][n][2] + bb);
                    pk.w = f2bf(acc[m][n][3] + bb);
                    *(u16x4*)(Vt + ((size_t)((b * H_ + h) * DH + dh)) * S_ + s) = pk;
                } else {
#pragma unroll
                    for (int i = 0; i < 4; i++) {
                        int r = rb + i, bb2 = r >> 11, s2 = r & (S_ - 1);
                        dst[((size_t)((bb2 * H_ + h) * S_) + s2) * DH + dh] =
                            f2bf((acc[m][n][i] + bb) * scl);
                    }
                }
            }
        }
    }
}

// ---- flash attention (R8-green, structure FROZEN): swapped-operand -------
// grid 1024 flat (XCD-swizzled), 256 threads = 4 waves x 16 q-rows.
// Mask from the 1 MB bit-packed array (one u16 per lane per tile,
// L2-resident with free 16x head reuse), expanded to AND-words in regs.
__global__ __launch_bounds__(256, 4) void attn(const u16* __restrict__ Q,
                                               const u16* __restrict__ K,
                                               const u16* __restrict__ V,
                                               const u16* __restrict__ mb,
                                               u16* __restrict__ ctx) {
    __shared__ u16 sK[2][64 * 64];   // [kk][d], swizzled, double-buffered
    __shared__ u16 sV[2][64 * 64];   // [d][kk], swizzled, double-buffered
    __shared__ u16 sP[4][16 * 64];   // per-wave [q=lr][k], unit-swizzled
    const int tid = threadIdx.x, lane = tid & 63, wid = tid >> 6;
    const int g = lane >> 4, lr = lane & 15, swz = lr & 7;
    const int swg = (blockIdx.x & 7) * 128 + (blockIdx.x >> 3);
    const int q0 = (swg & 31) * 64, h = (swg >> 5) & 15, b = swg >> 9;
    const u16* qb = Q + ((size_t)(b * H_ + h) * S_ + q0) * DH;
    const u16* kb = K + (size_t)(b * H_ + h) * S_ * DH;
    const u16* vb = V + (size_t)(b * H_ + h) * DH * S_;
    const u16* mbb = mb + (size_t)(b * 128 + (q0 >> 4) + wid) * 2048 + lane;
    u16* sPw = sP[wid];

    s16x8 qf[2];
#pragma unroll
    for (int dc = 0; dc < 2; dc++)
        qf[dc] = *(const s16x8*)(qb + (wid * 16 + lr) * DH + dc * 32 + g * 8);

    const u16 ov = (lr == 0) ? (u16)0x3F80 : (u16)0;
    s16x8 ones;
#pragma unroll
    for (int i = 0; i < 8; i++) ones[i] = (short)ov;

    f32x4 o[4] = {};
    f32x4 ol = {};  // ol[0] on lanes g==0 accumulates l(q=lr)
    float mrun = -3e38f;
    s16x8 kv[2], vv[2];
    u32x2 mmc[4];
    unsigned bitn = 0;

#pragma unroll
    for (int p = 0; p < 2; p++) {
        int L = p * 256 + tid;
        kv[p] = *(const s16x8*)(kb + (L >> 3) * DH + (L & 7) * 8);
        vv[p] = *(const s16x8*)(vb + (L >> 3) * S_ + (L & 7) * 8);
    }
    mexp16(mbb[0], mmc);
#pragma unroll
    for (int p = 0; p < 2; p++) {
        int L = p * 256 + tid;
        int rr = L >> 3, cc = L & 7;
        *(s16x8*)(sK[0] + rr * 64 + (cc ^ (rr & 7)) * 8) = kv[p];
        *(s16x8*)(sV[0] + rr * 64 + (cc ^ (rr & 7)) * 8) = vv[p];
    }
    __syncthreads();

    int cur = 0;
    for (int kt = 0; kt < S_ / 64; kt++) {
        const int k0 = kt * 64;
        if (kt < S_ / 64 - 1) {
            const int kn = k0 + 64;
            bitn = mbb[(kt + 1) * 64];
#pragma unroll
            for (int p = 0; p < 2; p++) {
                int L = p * 256 + tid;
                kv[p] = *(const s16x8*)(kb + (kn + (L >> 3)) * DH + (L & 7) * 8);
                vv[p] = *(const s16x8*)(vb + (L >> 3) * S_ + kn + (L & 7) * 8);
            }
        }

        const u16* sKc = sK[cur];
        const u16* sVc = sV[cur];
        f32x4 sc[4];
        __builtin_amdgcn_s_setprio(1);
#pragma unroll
        for (int n = 0; n < 4; n++) {
            const u16* kr = sKc + (n * 16 + lr) * 64;
            s16x8 kf0 = *(const s16x8*)(kr + (g ^ swz) * 8);
            s16x8 kf1 = *(const s16x8*)(kr + ((4 + g) ^ swz) * 8);
            f32x4 z = {0.f, 0.f, 0.f, 0.f};
            sc[n] = z;
            mfma(sc[n], kf0, qf[0]);
            mfma(sc[n], kf1, qf[1]);
        }
        __builtin_amdgcn_s_setprio(0);

        float t0 = max3f(sc[0][0], sc[0][1], sc[0][2]);
        float t1 = max3f(sc[0][3], sc[1][0], sc[1][1]);
        float t2 = max3f(sc[1][2], sc[1][3], sc[2][0]);
        float t3 = max3f(sc[2][1], sc[2][2], sc[2][3]);
        float t4 = max3f(sc[3][0], sc[3][1], sc[3][2]);
        float vm = fmaxf(max3f(max3f(t0, t1, sc[3][3]), t3, t4), t2);
        vm = fmaxf(vm, __shfl_xor(vm, 16));
        vm = fmaxf(vm, __shfl_xor(vm, 32));
        if (!__all(vm <= mrun + 8.f)) {  // defer-max (T13)
            float fac = __builtin_amdgcn_exp2f(mrun - vm);
            mrun = fmaxf(mrun, vm);
#pragma unroll
            for (int n = 0; n < 4; n++) o[n] *= fac;
            ol *= fac;
        }
#pragma unroll
        for (int n = 0; n < 4; n++) {
            u32x2 wp;
            wp.x = cvtpk(__builtin_amdgcn_exp2f(sc[n][0] - mrun),
                         __builtin_amdgcn_exp2f(sc[n][1] - mrun)) & mmc[n].x;
            wp.y = cvtpk(__builtin_amdgcn_exp2f(sc[n][2] - mrun),
                         __builtin_amdgcn_exp2f(sc[n][3] - mrun)) & mmc[n].y;
            int unit = (n * 2 + (g >> 1)) ^ swz;
            *(u32x2*)(sPw + lr * 64 + unit * 8 + (g & 1) * 4) = wp;
        }
        __builtin_amdgcn_s_setprio(1);
#pragma unroll
        for (int kc = 0; kc < 2; kc++) {
            s16x8 pb = *(const s16x8*)(sPw + lr * 64 + ((kc * 4 + g) ^ swz) * 8);
            mfma(ol, ones, pb);
#pragma unroll
            for (int n = 0; n < 4; n++) {
                int rv = n * 16 + lr;
                s16x8 vf = *(const s16x8*)(sVc + rv * 64 + ((kc * 4 + g) ^ (rv & 7)) * 8);
                mfma(o[n], vf, pb);
            }
        }
        __builtin_amdgcn_s_setprio(0);
        if (kt < S_ / 64 - 1) {
#pragma unroll
            for (int p = 0; p < 2; p++) {
                int L = p * 256 + tid;
                int rr = L >> 3, cc = L & 7;
                *(s16x8*)(sK[cur ^ 1] + rr * 64 + (cc ^ (rr & 7)) * 8) = kv[p];
                *(s16x8*)(sV[cur ^ 1] + rr * 64 + (cc ^ (rr & 7)) * 8) = vv[p];
            }
            mexp16(bitn, mmc);  // expand prefetched bits for next tile
            __syncthreads();
            cur ^= 1;
        }
    }
    {
        float lsum = __shfl(ol[0], lr);  // lane lr holds l(q=lr)
        float inv = 1.f / lsum;
#pragma unroll
        for (int n = 0; n < 4; n++) {
            u16x4 pk;
#pragma unroll
            for (int i = 0; i < 4; i++) pk[i] = f2bf(o[n][i] * inv);
            *(u16x4*)(sPw + lr * 64 + n * 16 + g * 4) = pk;
        }
#pragma unroll
        for (int half = 0; half < 2; half++) {
            int rr = half * 8 + (lane >> 3);
            s16x8 v = *(const s16x8*)(sPw + rr * 64 + (lane & 7) * 8);
            int q = q0 + wid * 16 + rr;
            *(s16x8*)(ctx + ((size_t)(b * S_ + q)) * E_ + h * DH + (lane & 7) * 8) = v;
        }
    }
}

// ---- launch -------------------------------------------------------------

extern "C" void kernel_launch(void* const* d_in, const int* in_sizes, int n_in,
                              void* d_out, int out_size, void* d_ws, size_t ws_size,
                              hipStream_t stream) {
    const float* x  = (const float*)d_in[0];
    const int* mask = (const int*)d_in[1];
    const float* Wq = (const float*)d_in[2]; const float* bq = (const float*)d_in[3];
    const float* Wk = (const float*)d_in[4]; const float* bk = (const float*)d_in[5];
    const float* Wv = (const float*)d_in[6]; const float* bv = (const float*)d_in[7];
    const float* Wo = (const float*)d_in[8]; const float* bo = (const float*)d_in[9];
    float* out = (float*)d_out;

    char* ws = (char*)d_ws;
    u16* xb     = (u16*)(ws);                      // 8 MB  [M,E] bf16
    u16* Wqkvt  = (u16*)(ws + (8u  << 20));        // 6 MB  [3072,1024] fused B^T
    u16* Wot    = (u16*)(ws + (14u << 20));        // 2 MB
    u16* Qh     = (u16*)(ws + (16u << 20));        // 8 MB  [B,H,S,64] (pre-scaled)
    u16* Kh     = (u16*)(ws + (24u << 20));        // 8 MB  [B,H,S,64]
    u16* Vt     = (u16*)(ws + (32u << 20));        // 8 MB  [B,H,64,S]
    u16* ctx    = (u16*)(ws + (40u << 20));        // 8 MB  [M,E]
    u16* mb     = (u16*)(ws + (48u << 20));        // 1 MB  bit-packed masks

    prep<<<5120, 256, 0, stream>>>(x, xb, Wq, Wk, Wv, Wo, Wqkvt, Wot);

    // 768 GEMM blocks + 256 mask-pack tail blocks (overlap, no shared deps)
    proj<0><<<(M_ / 128) * (3072 / 128) + 256, 256, 0, stream>>>(
        xb, Wqkvt, bq, bk, bv, Qh, Kh, Vt, nullptr, mask, mb);

    attn<<<(S_ / 64) * H_ * B_, 256, 0, stream>>>(Qh, Kh, Vt, mb, ctx);

    proj<3><<<(M_ / 128) * (E_ / 128), 256, 0, stream>>>(
        ctx, Wot, bo, nullptr, nullptr, nullptr, nullptr, nullptr, out, nullptr, nullptr);
}